// Round 1
// baseline (249.388 us; speedup 1.0000x reference)
//
#include <hip/hip_runtime.h>
#include <hip/hip_bf16.h>
#include <cstdint>
#include <cstddef>

#define EMB_K   1024
#define EMB_C   256
#define HWB     4096        // 64*64 per batch
#define NPIX    65536       // 16*4096
#define NELEM   16777216    // 16*256*64*64

typedef __bf16 bf16x8 __attribute__((ext_vector_type(8)));
typedef float  f32x4  __attribute__((ext_vector_type(4)));

// ---------------- init: argmin buffer + loss accumulator ----------------
__global__ void k_init(unsigned long long* __restrict__ packed, float* __restrict__ loss) {
  int i = blockIdx.x * blockDim.x + threadIdx.x;
  if (i < NPIX) packed[i] = ~0ull;
  if (i == 0) *loss = 0.f;
}

// ---------------- emb -> bf16 + fp32 squared norms ----------------
__global__ void k_emb(const float* __restrict__ emb, unsigned short* __restrict__ emb_bf,
                      float* __restrict__ enorm) {
  int k = blockIdx.x;      // 0..1023
  int c = threadIdx.x;     // 0..255
  float v = emb[(size_t)k * EMB_C + c];
  __hip_bfloat16 h = __float2bfloat16(v);
  emb_bf[(size_t)k * EMB_C + c] = __builtin_bit_cast(unsigned short, h);
  float s = v * v;
  for (int m = 32; m; m >>= 1) s += __shfl_down(s, m, 64);
  __shared__ float red[4];
  int lane = c & 63, w = c >> 6;
  if (lane == 0) red[w] = s;
  __syncthreads();
  if (c == 0) enorm[k] = red[0] + red[1] + red[2] + red[3];
}

// ---------------- x [b][c][hw] fp32 -> xT [n][c] bf16 (transpose+convert) ----------------
__global__ void k_xt(const float* __restrict__ x, unsigned short* __restrict__ xT) {
  __shared__ unsigned short tile[64][65];   // [c][hw], padded
  int hw0 = blockIdx.x * 64;
  int c0  = blockIdx.y * 64;
  int b   = blockIdx.z;
  int tid  = threadIdx.x;
  int lane = tid & 63, w = tid >> 6;
  const float* xb = x + (size_t)b * EMB_C * HWB;
#pragma unroll
  for (int i = 0; i < 16; ++i) {
    int cc = w * 16 + i;
    float v = xb[(size_t)(c0 + cc) * HWB + hw0 + lane];
    __hip_bfloat16 h = __float2bfloat16(v);
    tile[cc][lane] = __builtin_bit_cast(unsigned short, h);
  }
  __syncthreads();
  int n0 = b * HWB + hw0;
#pragma unroll
  for (int it = 0; it < 8; ++it) {
    int id = it * 256 + tid;
    int r  = id >> 5;         // hw offset 0..63
    int cp = id & 31;         // c pair 0..31
    unsigned val = (unsigned)tile[cp * 2][r] | ((unsigned)tile[cp * 2 + 1][r] << 16);
    *(unsigned*)(xT + (size_t)(n0 + r) * EMB_C + c0 + cp * 2) = val;
  }
}

// ---------------- GEMM + fused argmin ----------------
// D[n,k] = sum_c xT[n,c]*emb_bf[k,c]; track argmin_k (enorm[k] - 2*D[n,k])
#define BM 128
#define BN 128
#define BK 64

__global__ __launch_bounds__(256) void
k_gemm(const unsigned short* __restrict__ xT, const unsigned short* __restrict__ embbf,
       const float* __restrict__ enorm, unsigned long long* __restrict__ packed) {
  __shared__ __attribute__((aligned(16))) unsigned char As[BM * BK * 2];  // 16 KB
  __shared__ __attribute__((aligned(16))) unsigned char Bs[BN * BK * 2];  // 16 KB
  int k0 = blockIdx.x * BN;
  int n0 = blockIdx.y * BM;
  int tid  = threadIdx.x;
  int wave = tid >> 6, lane = tid & 63;
  int wm = wave >> 1, wn = wave & 1;
  int quad = lane >> 4, lr = lane & 15;

  f32x4 acc[4][4] = {};

  for (int ct = 0; ct < EMB_C; ct += BK) {
    if (ct) __syncthreads();
    // stage A/B tiles: 4 calls each, 16B/lane, XOR-swizzled 16B granules
#pragma unroll
    for (int j = 0; j < 4; ++j) {
      int gg = j * 256 + tid;          // chunk id 0..1023
      int r  = gg >> 3;                // tile row 0..127
      int jc = (gg & 7) ^ (r & 7);     // swizzled global 16B-chunk within row
      unsigned lds_off = (unsigned)(j * 4096 + (tid >> 6) * 1024);  // wave-uniform
      const unsigned short* ga = xT    + (size_t)(n0 + r) * EMB_C + ct + jc * 8;
      const unsigned short* gb = embbf + (size_t)(k0 + r) * EMB_C + ct + jc * 8;
      __builtin_amdgcn_global_load_lds((const __attribute__((address_space(1))) void*)ga,
                                       (__attribute__((address_space(3))) void*)(As + lds_off),
                                       16, 0, 0);
      __builtin_amdgcn_global_load_lds((const __attribute__((address_space(1))) void*)gb,
                                       (__attribute__((address_space(3))) void*)(Bs + lds_off),
                                       16, 0, 0);
    }
    __syncthreads();
#pragma unroll
    for (int s = 0; s < 2; ++s) {
      bf16x8 af[4], bfv[4];
#pragma unroll
      for (int i = 0; i < 4; ++i) {
        int r  = wm * 64 + i * 16 + lr;
        int ch = (s * 4 + quad) ^ (r & 7);
        af[i]  = *(const bf16x8*)(As + r * 128 + ch * 16);
        int rk  = wn * 64 + i * 16 + lr;
        int chb = (s * 4 + quad) ^ (rk & 7);
        bfv[i]  = *(const bf16x8*)(Bs + rk * 128 + chb * 16);
      }
#pragma unroll
      for (int i = 0; i < 4; ++i)
#pragma unroll
        for (int jj = 0; jj < 4; ++jj)
          acc[i][jj] = __builtin_amdgcn_mfma_f32_16x16x32_bf16(af[i], bfv[jj], acc[i][jj], 0, 0, 0);
    }
  }

  // fused argmin: d2 = enorm[k] - 2*dot. C/D layout: col=lane&15, row=quad*4+reg.
  float en[4];
#pragma unroll
  for (int j = 0; j < 4; ++j) en[j] = enorm[k0 + wn * 64 + j * 16 + lr];
#pragma unroll
  for (int i = 0; i < 4; ++i) {
#pragma unroll
    for (int r = 0; r < 4; ++r) {
      unsigned long long best = ~0ull;
#pragma unroll
      for (int j = 0; j < 4; ++j) {
        float d2 = en[j] - 2.0f * acc[i][j][r];
        unsigned u = __float_as_uint(d2);
        unsigned key = (u & 0x80000000u) ? ~u : (u | 0x80000000u);
        unsigned long long p = ((unsigned long long)key << 32) |
                               (unsigned)(k0 + wn * 64 + j * 16 + lr);
        if (p < best) best = p;
      }
      // reduce across the 16 lanes (same n, different k)
#pragma unroll
      for (int m = 1; m < 16; m <<= 1) {
        unsigned lo = (unsigned)best, hi = (unsigned)(best >> 32);
        lo = __shfl_xor(lo, m, 64);
        hi = __shfl_xor(hi, m, 64);
        unsigned long long o = ((unsigned long long)hi << 32) | lo;
        if (o < best) best = o;
      }
      if (lr == 0) {
        int n = n0 + wm * 64 + i * 16 + quad * 4 + r;
        atomicMin(&packed[n], best);
      }
    }
  }
}

// ---------------- epilogue: gather quant, write out, fused SSE ----------------
__global__ void k_epi(const float* __restrict__ x, const float* __restrict__ emb,
                      const unsigned long long* __restrict__ packed,
                      float* __restrict__ out, float* __restrict__ loss) {
  __shared__ int idx_s[64];
  __shared__ float red[4];
  int n0 = blockIdx.x * 64;
  int b   = n0 >> 12;        // /4096
  int hw0 = n0 & 4095;
  int tid  = threadIdx.x;
  int lane = tid & 63, w = tid >> 6;
  if (tid < 64) idx_s[tid] = (int)(packed[n0 + tid] & 0xFFFFFFFFull);
  __syncthreads();
  int idx = idx_s[lane];
  float lsum = 0.f;
  size_t xbase = (size_t)b * (EMB_C * HWB) + hw0 + lane;
  for (int c = w; c < EMB_C; c += 4) {
    size_t e = xbase + (size_t)c * HWB;
    float xv = x[e];
    float q  = emb[(size_t)idx * EMB_C + c];
    out[1 + e] = q;
    float d = q - xv;
    lsum += d * d;
  }
  for (int m = 32; m; m >>= 1) lsum += __shfl_down(lsum, m, 64);
  if (lane == 0) red[w] = lsum;
  __syncthreads();
  if (tid == 0) atomicAdd(loss, red[0] + red[1] + red[2] + red[3]);
}

// ---------------- finalize scalar loss ----------------
__global__ void k_fin(const float* __restrict__ loss, float* __restrict__ out) {
  // c_loss = q_latent + COMM_COST * e_latent = mse * (1 + 0.25*0.25)
  out[0] = 1.0625f * (*loss) / 16777216.0f;
}

extern "C" void kernel_launch(void* const* d_in, const int* in_sizes, int n_in,
                              void* d_out, int out_size, void* d_ws, size_t ws_size,
                              hipStream_t stream) {
  const float* x   = (const float*)d_in[0];   // [16,256,64,64]
  const float* emb = (const float*)d_in[1];   // [1024,256]
  float* out = (float*)d_out;                 // [1 + 16777216]
  char*  ws  = (char*)d_ws;

  unsigned short*     emb_bf = (unsigned short*)ws;                       // 512 KB
  float*              enorm  = (float*)(ws + 524288);                     // 4 KB
  unsigned long long* packed = (unsigned long long*)(ws + 528384);        // 512 KB
  float*              loss   = (float*)(ws + 1052672);                    // 4 B

  size_t xt_need = 1052736 + (size_t)NPIX * EMB_C * 2;                    // ~33.6 MB
  unsigned short* xT;
  if (ws_size >= xt_need) {
    xT = (unsigned short*)(ws + 1052736);     // 16B aligned
  } else {
    // fall back to scratch inside d_out's quant region (overwritten later by k_epi)
    xT = (unsigned short*)((char*)d_out + 16);
  }

  k_init<<<dim3(256), dim3(256), 0, stream>>>(packed, loss);
  k_emb <<<dim3(EMB_K), dim3(EMB_C), 0, stream>>>(emb, emb_bf, enorm);
  k_xt  <<<dim3(64, 4, 16), dim3(256), 0, stream>>>(x, xT);
  k_gemm<<<dim3(EMB_K / BN, NPIX / BM), dim3(256), 0, stream>>>(xT, emb_bf, enorm, packed);
  k_epi <<<dim3(NPIX / 64), dim3(256), 0, stream>>>(x, emb, packed, out, loss);
  k_fin <<<dim3(1), dim3(1), 0, stream>>>(loss, out);
}

// Round 2
// 207.940 us; speedup vs baseline: 1.1993x; 1.1993x over previous
//
#include <hip/hip_runtime.h>
#include <hip/hip_bf16.h>
#include <cstdint>
#include <cstddef>

#define EMB_K   1024
#define EMB_C   256
#define HWB     4096        // 64*64 per batch
#define NPIX    65536       // 16*4096
#define NELEM   16777216    // 16*256*64*64

typedef __bf16 bf16x8 __attribute__((ext_vector_type(8)));
typedef float  f32x4  __attribute__((ext_vector_type(4)));

__device__ __forceinline__ unsigned short bf16bits(float v) {
  __hip_bfloat16 h = __float2bfloat16(v);
  return __builtin_bit_cast(unsigned short, h);
}

// ---------------- init: keys buffer + loss accumulator ----------------
// key = (float_bits(f) & ~1023) | (1023-k), f = dot - 0.5*||e_k||^2 + 0.375 > 0
// so key 0 is below every valid key; argmax(key) == argmin(d2) with min-k tiebreak.
__global__ void k_init(unsigned* __restrict__ keys, float* __restrict__ loss) {
  int i = blockIdx.x * blockDim.x + threadIdx.x;
  if (i < NPIX) keys[i] = 0u;
  if (i == 0) *loss = 0.f;
}

// ---------------- emb -> bf16 + fp32 squared norms ----------------
__global__ void k_emb(const float* __restrict__ emb, unsigned short* __restrict__ emb_bf,
                      float* __restrict__ enorm) {
  int k = blockIdx.x;      // 0..1023
  int c = threadIdx.x;     // 0..255
  float v = emb[(size_t)k * EMB_C + c];
  emb_bf[(size_t)k * EMB_C + c] = bf16bits(v);
  float s = v * v;
  for (int m = 32; m; m >>= 1) s += __shfl_down(s, m, 64);
  __shared__ float red[4];
  int lane = c & 63, w = c >> 6;
  if (lane == 0) red[w] = s;
  __syncthreads();
  if (c == 0) enorm[k] = red[0] + red[1] + red[2] + red[3];
}

// ---- x [b][c][hw] fp32 -> xT [n][c] bf16 (transpose+convert) + xnorm[n] ----
__global__ void k_xt(const float* __restrict__ x, unsigned short* __restrict__ xT,
                     float* __restrict__ xnorm) {
  __shared__ unsigned short tile[64][65];   // [c][hw], padded
  __shared__ float xnred[4][64];
  int hw0 = blockIdx.x * 64;
  int b   = blockIdx.y;
  int tid  = threadIdx.x;
  int lane = tid & 63, w = tid >> 6;
  const float* xb = x + (size_t)b * EMB_C * HWB;
  int n0 = b * HWB + hw0;
  float xn = 0.f;
  for (int c0 = 0; c0 < EMB_C; c0 += 64) {
    if (c0) __syncthreads();
#pragma unroll
    for (int i = 0; i < 16; ++i) {
      int cc = w * 16 + i;
      float v = xb[(size_t)(c0 + cc) * HWB + hw0 + lane];
      xn += v * v;                       // hw = lane, this thread's cc-slice
      tile[cc][lane] = bf16bits(v);
    }
    __syncthreads();
#pragma unroll
    for (int it = 0; it < 8; ++it) {
      int id = it * 256 + tid;
      int r  = id >> 5;         // hw offset 0..63
      int cp = id & 31;         // c pair 0..31
      unsigned val = (unsigned)tile[cp * 2][r] | ((unsigned)tile[cp * 2 + 1][r] << 16);
      *(unsigned*)(xT + (size_t)(n0 + r) * EMB_C + c0 + cp * 2) = val;
    }
  }
  xnred[w][lane] = xn;
  __syncthreads();
  if (tid < 64)
    xnorm[n0 + tid] = xnred[0][tid] + xnred[1][tid] + xnred[2][tid] + xnred[3][tid];
}

// ---------------- GEMM + fused argmin (packed-f32 key, atomicMax) ----------------
#define BM 128
#define BN 128
#define BK 64

__global__ __launch_bounds__(256) void
k_gemm(const unsigned short* __restrict__ xT, const unsigned short* __restrict__ embbf,
       const float* __restrict__ enorm, unsigned* __restrict__ keys) {
  __shared__ __attribute__((aligned(16))) unsigned char As[BM * BK * 2];  // 16 KB
  __shared__ __attribute__((aligned(16))) unsigned char Bs[BN * BK * 2];  // 16 KB
  int k0 = blockIdx.x * BN;
  int n0 = blockIdx.y * BM;
  int tid  = threadIdx.x;
  int wave = tid >> 6, lane = tid & 63;
  int wm = wave >> 1, wn = wave & 1;
  int quad = lane >> 4, lr = lane & 15;

  f32x4 acc[4][4] = {};

#pragma unroll
  for (int ct = 0; ct < EMB_C; ct += BK) {
    if (ct) __syncthreads();
#pragma unroll
    for (int j = 0; j < 4; ++j) {
      int gg = j * 256 + tid;          // chunk id 0..1023
      int r  = gg >> 3;                // tile row 0..127
      int jc = (gg & 7) ^ (r & 7);     // swizzled 16B-chunk within row
      unsigned lds_off = (unsigned)(j * 4096 + (tid >> 6) * 1024);  // wave-uniform
      const unsigned short* ga = xT    + (size_t)(n0 + r) * EMB_C + ct + jc * 8;
      const unsigned short* gb = embbf + (size_t)(k0 + r) * EMB_C + ct + jc * 8;
      __builtin_amdgcn_global_load_lds((const __attribute__((address_space(1))) void*)ga,
                                       (__attribute__((address_space(3))) void*)(As + lds_off),
                                       16, 0, 0);
      __builtin_amdgcn_global_load_lds((const __attribute__((address_space(1))) void*)gb,
                                       (__attribute__((address_space(3))) void*)(Bs + lds_off),
                                       16, 0, 0);
    }
    __syncthreads();
#pragma unroll
    for (int s = 0; s < 2; ++s) {
      bf16x8 af[4], bfv[4];
#pragma unroll
      for (int i = 0; i < 4; ++i) {
        int r  = wm * 64 + i * 16 + lr;
        int ch = (s * 4 + quad) ^ (r & 7);
        af[i]  = *(const bf16x8*)(As + r * 128 + ch * 16);
        int rk  = wn * 64 + i * 16 + lr;
        int chb = (s * 4 + quad) ^ (rk & 7);
        bfv[i]  = *(const bf16x8*)(Bs + rk * 128 + chb * 16);
      }
#pragma unroll
      for (int i = 0; i < 4; ++i)
#pragma unroll
        for (int jj = 0; jj < 4; ++jj)
          acc[i][jj] = __builtin_amdgcn_mfma_f32_16x16x32_bf16(af[i], bfv[jj], acc[i][jj], 0, 0, 0);
    }
  }

  // argmax of f = dot + (0.375 - 0.5*enorm[k]); f in (0.04, 0.71) -> positive-float
  // u32 compare is order-correct; low 10 mantissa bits carry (1023-k).
  float    cj[4];
  unsigned kp[4];
#pragma unroll
  for (int j = 0; j < 4; ++j) {
    int k = k0 + wn * 64 + j * 16 + lr;
    cj[j] = 0.375f - 0.5f * enorm[k];
    kp[j] = 1023u - (unsigned)k;
  }
#pragma unroll
  for (int i = 0; i < 4; ++i) {
#pragma unroll
    for (int r = 0; r < 4; ++r) {
      unsigned best = 0u;
#pragma unroll
      for (int j = 0; j < 4; ++j) {
        float f = acc[i][j][r] + cj[j];
        unsigned key = (__float_as_uint(f) & 0xFFFFFC00u) | kp[j];
        best = best > key ? best : key;
      }
#pragma unroll
      for (int m = 1; m < 16; m <<= 1) {
        unsigned o = (unsigned)__shfl_xor((int)best, m, 64);
        best = best > o ? best : o;
      }
      if (lr == 0) {
        int n = n0 + wm * 64 + i * 16 + quad * 4 + r;
        atomicMax(&keys[n], best);
      }
    }
  }
}

// -------- epilogue: gather quant rows (no x re-read), loss from keys --------
__global__ void k_epi(const float* __restrict__ emb, const unsigned* __restrict__ keys,
                      const float* __restrict__ xnorm,
                      float* __restrict__ out, float* __restrict__ loss) {
  __shared__ int idx_s[64];
  int n0 = blockIdx.x * 64;
  int b   = n0 >> 12;
  int hw0 = n0 & 4095;
  int tid  = threadIdx.x;
  int lane = tid & 63, w = tid >> 6;
  if (tid < 64) idx_s[tid] = 1023 - (int)(keys[n0 + tid] & 1023u);
  __syncthreads();
  int idx = idx_s[lane];
  const float* er = emb + (size_t)idx * EMB_C;
  float* ob = out + 1 + (size_t)b * (EMB_C * HWB) + hw0 + lane;
#pragma unroll
  for (int cc = 0; cc < 16; ++cc) {
    int c = w * 64 + cc * 4;
    f32x4 q = *(const f32x4*)(er + c);       // 16B gather from L2-resident emb
    ob[(size_t)(c + 0) * HWB] = q[0];
    ob[(size_t)(c + 1) * HWB] = q[1];
    ob[(size_t)(c + 2) * HWB] = q[2];
    ob[(size_t)(c + 3) * HWB] = q[3];
  }
  if (tid < 64) {   // wave 0: loss partial; d2 = xnorm + 0.75 - 2*f_hat
    unsigned key = keys[n0 + tid];
    float fh = __uint_as_float(key & 0xFFFFFC00u);
    float term = xnorm[n0 + tid] + 0.75f - 2.0f * fh;
    for (int m = 32; m; m >>= 1) term += __shfl_down(term, m, 64);
    if (tid == 0) atomicAdd(loss, term);
  }
}

// ---------------- finalize scalar loss ----------------
__global__ void k_fin(const float* __restrict__ loss, float* __restrict__ out) {
  out[0] = 1.0625f * (*loss) / 16777216.0f;   // (1 + 0.25*0.25) * mse
}

extern "C" void kernel_launch(void* const* d_in, const int* in_sizes, int n_in,
                              void* d_out, int out_size, void* d_ws, size_t ws_size,
                              hipStream_t stream) {
  const float* x   = (const float*)d_in[0];   // [16,256,64,64]
  const float* emb = (const float*)d_in[1];   // [1024,256]
  float* out = (float*)d_out;                 // [1 + 16777216]
  char*  ws  = (char*)d_ws;

  unsigned short* emb_bf = (unsigned short*)ws;                 // 512 KB
  float*          enorm  = (float*)(ws + 524288);               // 4 KB
  unsigned*       keys   = (unsigned*)(ws + 528384);            // 256 KB
  float*          xnorm  = (float*)(ws + 790528);               // 256 KB
  float*          loss   = (float*)(ws + 1052672);              // 4 B (pad to 64)

  size_t xt_need = 1052736 + (size_t)NPIX * EMB_C * 2;          // ~34.6 MB
  unsigned short* xT;
  if (ws_size >= xt_need) {
    xT = (unsigned short*)(ws + 1052736);
  } else {
    // scratch inside d_out's quant region; k_gemm consumes xT before k_epi writes out
    xT = (unsigned short*)((char*)d_out + 16);
  }

  k_init<<<dim3(256), dim3(256), 0, stream>>>(keys, loss);
  k_emb <<<dim3(EMB_K), dim3(EMB_C), 0, stream>>>(emb, emb_bf, enorm);
  k_xt  <<<dim3(64, 16), dim3(256), 0, stream>>>(x, xT, xnorm);
  k_gemm<<<dim3(EMB_K / BN, NPIX / BM), dim3(256), 0, stream>>>(xT, emb_bf, enorm, keys);
  k_epi <<<dim3(NPIX / 64), dim3(256), 0, stream>>>(emb, keys, xnorm, out, loss);
  k_fin <<<dim3(1), dim3(1), 0, stream>>>(loss, out);
}